// Round 1
// baseline (513.281 us; speedup 1.0000x reference)
//
#include <hip/hip_runtime.h>
#include <hip/hip_bf16.h>

#define T 512
#define H 128
#define V 32000
#define B 2

typedef __attribute__((ext_vector_type(8))) short bf16x8;
typedef __attribute__((ext_vector_type(4))) float f32x4;

__device__ __forceinline__ unsigned short f2bf(float f){
  unsigned int u = __float_as_uint(f);
  u = (u + 0x7FFFu + ((u >> 16) & 1u)) >> 16;
  return (unsigned short)u;
}

__device__ __forceinline__ float fast_tanh(float x){
  x = fminf(8.f, fmaxf(-8.f, x));
  float e = __expf(2.f * x);
  return (e - 1.f) / (e + 1.f);
}

// ---------------- Kernel 1: embedding gather + input projection ----------------
// xp[b,t,i] = sum_e table[x[bt],e] * W_ih[i,e] + b_ih[i] + b_hh[i]
__global__ __launch_bounds__(128) void embed_kernel(const int* __restrict__ x,
    const float* __restrict__ table, const float* __restrict__ W_ih,
    const float* __restrict__ b_ih, const float* __restrict__ b_hh,
    float* __restrict__ xp){
  int bt = blockIdx.x;
  int i = threadIdx.x;
  __shared__ __align__(16) float e[32];
  if (i < 32) e[i] = table[(size_t)x[bt] * 32 + i];
  __syncthreads();
  const float* wr = W_ih + i * 32;
  float a0 = 0.f, a1 = 0.f, a2 = 0.f, a3 = 0.f;
  #pragma unroll
  for (int k = 0; k < 32; k += 4){
    float4 w4 = *(const float4*)(wr + k);
    float4 e4 = *(const float4*)(e + k);
    a0 += w4.x * e4.x; a1 += w4.y * e4.y; a2 += w4.z * e4.z; a3 += w4.w * e4.w;
  }
  xp[(size_t)bt * H + i] = (a0 + a1) + (a2 + a3) + b_ih[i] + b_hh[i];
}

// ---------------- Kernel 2: serial RNN scan, one block per batch chain ----------------
// 256 threads: thread t -> output i = t>>1, k-half = t&1. W_hh rows in registers,
// h double-buffered in LDS, xp prefetched one step ahead.
__global__ __launch_bounds__(256) void rnn_kernel(const float* __restrict__ xp,
    const float* __restrict__ hidden, const float* __restrict__ W_hh,
    float* __restrict__ rnn, float* __restrict__ hid_out){
  int b = blockIdx.x;
  int tid = threadIdx.x;
  int i = tid >> 1, half = tid & 1;
  float w[64];
  const float* wrow = W_hh + (size_t)i * H + half * 64;
  #pragma unroll
  for (int j = 0; j < 64; ++j) w[j] = wrow[j];
  __shared__ __align__(16) float hb[2][H];
  if (half == 0) hb[0][i] = hidden[b * H + i];
  __syncthreads();
  const float* xpp = xp + (size_t)b * T * H + i;
  float xv = xpp[0];
  float hn = 0.f;
  int cur = 0;
  for (int step = 0; step < T; ++step){
    float xn = (step < T - 1) ? xpp[(size_t)(step + 1) * H] : 0.f;
    const float* hs = hb[cur] + half * 64;
    float a0 = 0.f, a1 = 0.f, a2 = 0.f, a3 = 0.f;
    #pragma unroll
    for (int j = 0; j < 16; ++j){
      float4 hv = *(const float4*)(hs + j * 4);
      a0 += hv.x * w[4*j];   a1 += hv.y * w[4*j+1];
      a2 += hv.z * w[4*j+2]; a3 += hv.w * w[4*j+3];
    }
    float sum = (a0 + a1) + (a2 + a3);
    sum += __shfl_xor(sum, 1);
    hn = fast_tanh(xv + sum);
    if (half == 0){
      hb[cur ^ 1][i] = hn;
      rnn[(size_t)b * T * H + (size_t)step * H + i] = hn;
    }
    __syncthreads();
    xv = xn;
    cur ^= 1;
  }
  if (half == 0) hid_out[b * H + i] = hn;
}

// ---------------- Kernel 3: query/key projections ----------------
__global__ __launch_bounds__(256) void qk_kernel(const float* __restrict__ rnn,
    const float* __restrict__ W1, const float* __restrict__ W2,
    float* __restrict__ q, float* __restrict__ ky){
  int bt = blockIdx.x;
  int tid = threadIdx.x;
  __shared__ __align__(16) float r[H];
  if (tid < H) r[tid] = rnn[(size_t)bt * H + tid];
  __syncthreads();
  int i = tid & (H - 1);
  const float* wrow = ((tid < H) ? W1 : W2) + (size_t)i * H;
  float a0 = 0.f, a1 = 0.f, a2 = 0.f, a3 = 0.f;
  #pragma unroll 8
  for (int k = 0; k < H; k += 4){
    float4 w4 = *(const float4*)(wrow + k);
    float4 r4 = *(const float4*)(r + k);
    a0 += w4.x * r4.x; a1 += w4.y * r4.y; a2 += w4.z * r4.z; a3 += w4.w * r4.w;
  }
  float res = (a0 + a1) + (a2 + a3);
  if (tid < H) q[(size_t)bt * H + i] = res;
  else         ky[(size_t)bt * H + i] = res;
}

// ---------------- Kernel 4: attention scores + softmax + context + Wp/relu ----------------
__global__ __launch_bounds__(256) void attn_kernel(const float* __restrict__ rnn,
    const float* __restrict__ q, const float* __restrict__ ky,
    const float* __restrict__ v, const float* __restrict__ Wp,
    const float* __restrict__ bp, float* __restrict__ wout,
    unsigned short* __restrict__ outb){
  int bt = blockIdx.x;
  int b = bt >> 9, t = bt & (T - 1);
  int tid = threadIdx.x;
  __shared__ __align__(16) float qL[H], vL[H], rrL[H], ctxL[H];
  __shared__ __align__(16) float scL[T], wL[T];
  __shared__ float red[4], red2[4];
  if (tid < H){
    qL[tid]  = q[(size_t)bt * H + tid];
    vL[tid]  = v[tid];
    rrL[tid] = rnn[(size_t)bt * H + tid];
  }
  __syncthreads();
  // scores: thread per s
  for (int s = tid; s < T; s += 256){
    float sc = -1e30f;
    if (s <= t){
      const float* kr = ky + (size_t)(b * T + s) * H;
      float a0 = 0.f, a1 = 0.f, a2 = 0.f, a3 = 0.f;
      #pragma unroll 4
      for (int h = 0; h < H; h += 4){
        float4 kv = *(const float4*)(kr + h);
        float4 qv = *(const float4*)(qL + h);
        float4 vv = *(const float4*)(vL + h);
        a0 += fast_tanh(qv.x + kv.x) * vv.x;
        a1 += fast_tanh(qv.y + kv.y) * vv.y;
        a2 += fast_tanh(qv.z + kv.z) * vv.z;
        a3 += fast_tanh(qv.w + kv.w) * vv.w;
      }
      sc = (a0 + a1) + (a2 + a3);
    }
    scL[s] = sc;
  }
  __syncthreads();
  // block max
  float m = -1e30f;
  for (int s = tid; s < T; s += 256) m = fmaxf(m, scL[s]);
  #pragma unroll
  for (int o = 32; o > 0; o >>= 1) m = fmaxf(m, __shfl_xor(m, o));
  if ((tid & 63) == 0) red[tid >> 6] = m;
  __syncthreads();
  float mx = fmaxf(fmaxf(red[0], red[1]), fmaxf(red[2], red[3]));
  // exp + block sum
  float ls = 0.f;
  for (int s = tid; s < T; s += 256){
    float e = (s <= t) ? __expf(scL[s] - mx) : 0.f;
    wL[s] = e; ls += e;
  }
  #pragma unroll
  for (int o = 32; o > 0; o >>= 1) ls += __shfl_xor(ls, o);
  if ((tid & 63) == 0) red2[tid >> 6] = ls;
  __syncthreads();
  float inv = 1.f / (red2[0] + red2[1] + red2[2] + red2[3]);
  for (int s = tid; s < T; s += 256){
    float wv = wL[s] * inv;
    wL[s] = wv;
    wout[(size_t)bt * T + s] = wv;
  }
  __syncthreads();
  // context: thread per h
  if (tid < H){
    const float* rb = rnn + (size_t)b * T * H + tid;
    float c0 = 0.f, c1 = 0.f, c2 = 0.f, c3 = 0.f;
    int s = 0;
    for (; s + 3 <= t; s += 4){
      c0 += wL[s]     * rb[(size_t)s * H];
      c1 += wL[s + 1] * rb[(size_t)(s + 1) * H];
      c2 += wL[s + 2] * rb[(size_t)(s + 2) * H];
      c3 += wL[s + 3] * rb[(size_t)(s + 3) * H];
    }
    for (; s <= t; ++s) c0 += wL[s] * rb[(size_t)s * H];
    ctxL[tid] = (c0 + c1) + (c2 + c3);
  }
  __syncthreads();
  // out = relu([rnn_row, ctx] @ Wp.T + bp), store bf16
  if (tid < H){
    const float* wp = Wp + (size_t)tid * (2 * H);
    float a0 = 0.f, a1 = 0.f, a2 = 0.f, a3 = 0.f;
    #pragma unroll 8
    for (int k = 0; k < H; k += 4){
      float4 w4 = *(const float4*)(wp + k);
      float4 r4 = *(const float4*)(rrL + k);
      a0 += w4.x * r4.x; a1 += w4.y * r4.y; a2 += w4.z * r4.z; a3 += w4.w * r4.w;
    }
    #pragma unroll 8
    for (int k = 0; k < H; k += 4){
      float4 w4 = *(const float4*)(wp + H + k);
      float4 c4 = *(const float4*)(ctxL + k);
      a0 += w4.x * c4.x; a1 += w4.y * c4.y; a2 += w4.z * c4.z; a3 += w4.w * c4.w;
    }
    float o = bp[tid] + (a0 + a1) + (a2 + a3);
    o = fmaxf(o, 0.f);
    outb[(size_t)bt * H + tid] = f2bf(o);
  }
}

// ---------------- Kernel 5: Wfc f32 -> bf16 ----------------
__global__ __launch_bounds__(256) void cvt_kernel(const float* __restrict__ src,
    unsigned short* __restrict__ dst){
  size_t idx = ((size_t)blockIdx.x * 256 + threadIdx.x) * 4;
  float4 f = *(const float4*)(src + idx);
  ushort4 o;
  o.x = f2bf(f.x); o.y = f2bf(f.y); o.z = f2bf(f.z); o.w = f2bf(f.w);
  *(ushort4*)(dst + idx) = o;
}

// ---------------- Kernel 6: logits = out @ Wfc.T + bfc  (bf16 MFMA) ----------------
// C[m][n] = sum_k A[m][k] * W[n][k];  A: 1024x128 bf16, W: 32000x128 bf16.
// Block tile: 64(M) x 128(N), 4 waves, wave w owns rows [16w,16w+16) x all 8 n-subtiles.
__global__ __launch_bounds__(256) void gemm_kernel(const unsigned short* __restrict__ Ab,
    const unsigned short* __restrict__ Bb, const float* __restrict__ bfc,
    float* __restrict__ Cout){
  __shared__ __align__(16) unsigned short As[64 * 136];
  __shared__ __align__(16) unsigned short Bs[128 * 136];
  int tid = threadIdx.x;
  int nBase = blockIdx.x * 128;
  int mBase = blockIdx.y * 64;
  #pragma unroll
  for (int it = 0; it < 4; ++it){
    int idx = tid + it * 256;
    int row = idx >> 4, kc = (idx & 15) * 8;
    uint4 d = *(const uint4*)(Ab + (size_t)(mBase + row) * H + kc);
    *(uint4*)(As + row * 136 + kc) = d;
  }
  #pragma unroll
  for (int it = 0; it < 8; ++it){
    int idx = tid + it * 256;
    int row = idx >> 4, kc = (idx & 15) * 8;
    uint4 d = *(const uint4*)(Bb + (size_t)(nBase + row) * H + kc);
    *(uint4*)(Bs + row * 136 + kc) = d;
  }
  __syncthreads();
  int l = tid & 63, wv = tid >> 6;
  f32x4 acc[8];
  #pragma unroll
  for (int i = 0; i < 8; ++i) acc[i] = (f32x4){0.f, 0.f, 0.f, 0.f};
  const unsigned short* Ap = As + (wv * 16 + (l & 15)) * 136 + (l >> 4) * 8;
  const unsigned short* Bp = Bs + (l & 15) * 136 + (l >> 4) * 8;
  #pragma unroll
  for (int k0 = 0; k0 < 128; k0 += 32){
    bf16x8 af = *(const bf16x8*)(Ap + k0);
    #pragma unroll
    for (int sub = 0; sub < 8; ++sub){
      bf16x8 bfr = *(const bf16x8*)(Bp + sub * 16 * 136 + k0);
      acc[sub] = __builtin_amdgcn_mfma_f32_16x16x32_bf16(af, bfr, acc[sub], 0, 0, 0);
    }
  }
  int row0 = mBase + wv * 16 + (l >> 4) * 4;
  int col0 = nBase + (l & 15);
  #pragma unroll
  for (int sub = 0; sub < 8; ++sub){
    int c = col0 + sub * 16;
    float bias = bfc[c];
    #pragma unroll
    for (int r = 0; r < 4; ++r){
      Cout[(size_t)(row0 + r) * V + c] = acc[sub][r] + bias;
    }
  }
}

extern "C" void kernel_launch(void* const* d_in, const int* in_sizes, int n_in,
                              void* d_out, int out_size, void* d_ws, size_t ws_size,
                              hipStream_t stream){
  const int*   x      = (const int*)d_in[0];
  const float* hidden = (const float*)d_in[1];
  const float* table  = (const float*)d_in[2];
  const float* W_ih   = (const float*)d_in[3];
  const float* W_hh   = (const float*)d_in[4];
  const float* b_ih   = (const float*)d_in[5];
  const float* b_hh   = (const float*)d_in[6];
  const float* W1     = (const float*)d_in[7];
  const float* W2     = (const float*)d_in[8];
  const float* v      = (const float*)d_in[9];
  const float* Wp     = (const float*)d_in[10];
  const float* bp     = (const float*)d_in[11];
  const float* Wfc    = (const float*)d_in[12];
  const float* bfc    = (const float*)d_in[13];

  float* out     = (float*)d_out;
  float* logits  = out;                              // (B,T,V)
  float* hid_out = out + (size_t)B * T * V;          // (1,B,H)
  float* w_out   = hid_out + (size_t)B * H;          // (B,T,T)

  float* xp  = (float*)d_ws;
  float* rnn = xp  + (size_t)B * T * H;
  float* q   = rnn + (size_t)B * T * H;
  float* ky  = q   + (size_t)B * T * H;
  unsigned short* outb = (unsigned short*)(ky + (size_t)B * T * H);
  unsigned short* wfcb = outb + (size_t)B * T * H;

  embed_kernel<<<B * T, 128, 0, stream>>>(x, table, W_ih, b_ih, b_hh, xp);
  rnn_kernel<<<B, 256, 0, stream>>>(xp, hidden, W_hh, rnn, hid_out);
  qk_kernel<<<B * T, 256, 0, stream>>>(rnn, W1, W2, q, ky);
  attn_kernel<<<B * T, 256, 0, stream>>>(rnn, q, ky, v, Wp, bp, w_out, outb);
  cvt_kernel<<<(V * H) / 1024, 256, 0, stream>>>(Wfc, wfcb);
  gemm_kernel<<<dim3(V / 128, (B * T) / 64), 256, 0, stream>>>(outb, wfcb, bfc, logits);
}

// Round 2
// 494.482 us; speedup vs baseline: 1.0380x; 1.0380x over previous
//
#include <hip/hip_runtime.h>
#include <hip/hip_bf16.h>

#define T 512
#define H 128
#define V 32000
#define B 2

typedef __attribute__((ext_vector_type(8))) short bf16x8;
typedef __attribute__((ext_vector_type(4))) float f32x4;

__device__ __forceinline__ unsigned short f2bf(float f){
  unsigned int u = __float_as_uint(f);
  u = (u + 0x7FFFu + ((u >> 16) & 1u)) >> 16;
  return (unsigned short)u;
}

__device__ __forceinline__ float fast_tanh(float x){
  x = fminf(8.f, fmaxf(-8.f, x));
  float e = __expf(2.f * x);
  return (e - 1.f) / (e + 1.f);
}

// ---------------- Kernel 1: prep = embedding/input-projection + Wfc->bf16 ----------------
// blocks [0, B*T): xp[b,t,i] = sum_e table[x[bt],e] * W_ih[i,e] + b_ih[i] + b_hh[i]
// blocks [B*T, B*T+4000): convert Wfc (32000x128 f32) to bf16, 1024 elems/block
__global__ __launch_bounds__(128) void prep_kernel(const int* __restrict__ x,
    const float* __restrict__ table, const float* __restrict__ W_ih,
    const float* __restrict__ b_ih, const float* __restrict__ b_hh,
    const float* __restrict__ Wfc,
    float* __restrict__ xp, unsigned short* __restrict__ wfcb){
  int blk = blockIdx.x;
  int tid = threadIdx.x;
  __shared__ __align__(16) float e[32];
  if (blk < B * T){
    if (tid < 32) e[tid] = table[(size_t)x[blk] * 32 + tid];
    __syncthreads();
    const float* wr = W_ih + tid * 32;
    float a0 = 0.f, a1 = 0.f, a2 = 0.f, a3 = 0.f;
    #pragma unroll
    for (int k = 0; k < 32; k += 4){
      float4 w4 = *(const float4*)(wr + k);
      float4 e4 = *(const float4*)(e + k);
      a0 += w4.x * e4.x; a1 += w4.y * e4.y; a2 += w4.z * e4.z; a3 += w4.w * e4.w;
    }
    xp[(size_t)blk * H + tid] = (a0 + a1) + (a2 + a3) + b_ih[tid] + b_hh[tid];
  } else {
    size_t base = (size_t)(blk - B * T) * 1024 + (size_t)tid * 8;
    float4 f0 = *(const float4*)(Wfc + base);
    float4 f1 = *(const float4*)(Wfc + base + 4);
    ushort4 o0, o1;
    o0.x = f2bf(f0.x); o0.y = f2bf(f0.y); o0.z = f2bf(f0.z); o0.w = f2bf(f0.w);
    o1.x = f2bf(f1.x); o1.y = f2bf(f1.y); o1.z = f2bf(f1.z); o1.w = f2bf(f1.w);
    *(ushort4*)(wfcb + base) = o0;
    *(ushort4*)(wfcb + base + 4) = o1;
  }
}

// ---------------- Kernel 2: serial RNN scan, one block per batch chain ----------------
// 256 threads: thread t -> output i = t>>1, k-half = t&1. W_hh rows in registers
// (launch_bounds(.,1) so the 64-float cache does NOT spill), h double-buffered in
// LDS, xp prefetched one step ahead.
__global__ __launch_bounds__(256, 1) void rnn_kernel(const float* __restrict__ xp,
    const float* __restrict__ hidden, const float* __restrict__ W_hh,
    float* __restrict__ rnn, float* __restrict__ hid_out){
  int b = blockIdx.x;
  int tid = threadIdx.x;
  int i = tid >> 1, half = tid & 1;
  float w[64];
  const float* wrow = W_hh + (size_t)i * H + half * 64;
  #pragma unroll
  for (int j = 0; j < 64; j += 4){
    float4 t4 = *(const float4*)(wrow + j);
    w[j] = t4.x; w[j+1] = t4.y; w[j+2] = t4.z; w[j+3] = t4.w;
  }
  __shared__ __align__(16) float hb[2][H];
  if (half == 0) hb[0][i] = hidden[b * H + i];
  __syncthreads();
  const float* xpp = xp + (size_t)b * T * H + i;
  float xv = xpp[0];
  float hn = 0.f;
  int cur = 0;
  for (int step = 0; step < T; ++step){
    float xn = (step < T - 1) ? xpp[(size_t)(step + 1) * H] : 0.f;
    const float* hs = hb[cur] + half * 64;
    float a0 = 0.f, a1 = 0.f, a2 = 0.f, a3 = 0.f;
    #pragma unroll
    for (int j = 0; j < 16; ++j){
      float4 hv = *(const float4*)(hs + j * 4);
      a0 += hv.x * w[4*j];   a1 += hv.y * w[4*j+1];
      a2 += hv.z * w[4*j+2]; a3 += hv.w * w[4*j+3];
    }
    float sum = (a0 + a1) + (a2 + a3);
    sum += __shfl_xor(sum, 1);
    hn = fast_tanh(xv + sum);
    if (half == 0){
      hb[cur ^ 1][i] = hn;
      rnn[(size_t)b * T * H + (size_t)step * H + i] = hn;
    }
    __syncthreads();
    xv = xn;
    cur ^= 1;
  }
  if (half == 0) hid_out[b * H + i] = hn;
}

// ---------------- Kernel 3: query/key projections ----------------
__global__ __launch_bounds__(256) void qk_kernel(const float* __restrict__ rnn,
    const float* __restrict__ W1, const float* __restrict__ W2,
    float* __restrict__ q, float* __restrict__ ky){
  int bt = blockIdx.x;
  int tid = threadIdx.x;
  __shared__ __align__(16) float r[H];
  if (tid < H) r[tid] = rnn[(size_t)bt * H + tid];
  __syncthreads();
  int i = tid & (H - 1);
  const float* wrow = ((tid < H) ? W1 : W2) + (size_t)i * H;
  float a0 = 0.f, a1 = 0.f, a2 = 0.f, a3 = 0.f;
  #pragma unroll 8
  for (int k = 0; k < H; k += 4){
    float4 w4 = *(const float4*)(wrow + k);
    float4 r4 = *(const float4*)(r + k);
    a0 += w4.x * r4.x; a1 += w4.y * r4.y; a2 += w4.z * r4.z; a3 += w4.w * r4.w;
  }
  float res = (a0 + a1) + (a2 + a3);
  if (tid < H) q[(size_t)bt * H + i] = res;
  else         ky[(size_t)bt * H + i] = res;
}

// ---------------- Kernel 4: attention scores + softmax + context + Wp/relu ----------------
__global__ __launch_bounds__(256) void attn_kernel(const float* __restrict__ rnn,
    const float* __restrict__ q, const float* __restrict__ ky,
    const float* __restrict__ v, const float* __restrict__ Wp,
    const float* __restrict__ bp, float* __restrict__ wout,
    unsigned short* __restrict__ outb){
  int bt = blockIdx.x;
  int b = bt >> 9, t = bt & (T - 1);
  int tid = threadIdx.x;
  __shared__ __align__(16) float qL[H], vL[H], rrL[H], ctxL[H];
  __shared__ __align__(16) float scL[T], wL[T];
  __shared__ float red[4], red2[4];
  if (tid < H){
    qL[tid]  = q[(size_t)bt * H + tid];
    vL[tid]  = v[tid];
    rrL[tid] = rnn[(size_t)bt * H + tid];
  }
  __syncthreads();
  // scores: thread per s
  for (int s = tid; s < T; s += 256){
    float sc = -1e30f;
    if (s <= t){
      const float* kr = ky + (size_t)(b * T + s) * H;
      float a0 = 0.f, a1 = 0.f, a2 = 0.f, a3 = 0.f;
      #pragma unroll 4
      for (int h = 0; h < H; h += 4){
        float4 kv = *(const float4*)(kr + h);
        float4 qv = *(const float4*)(qL + h);
        float4 vv = *(const float4*)(vL + h);
        a0 += fast_tanh(qv.x + kv.x) * vv.x;
        a1 += fast_tanh(qv.y + kv.y) * vv.y;
        a2 += fast_tanh(qv.z + kv.z) * vv.z;
        a3 += fast_tanh(qv.w + kv.w) * vv.w;
      }
      sc = (a0 + a1) + (a2 + a3);
    }
    scL[s] = sc;
  }
  __syncthreads();
  // block max
  float m = -1e30f;
  for (int s = tid; s < T; s += 256) m = fmaxf(m, scL[s]);
  #pragma unroll
  for (int o = 32; o > 0; o >>= 1) m = fmaxf(m, __shfl_xor(m, o));
  if ((tid & 63) == 0) red[tid >> 6] = m;
  __syncthreads();
  float mx = fmaxf(fmaxf(red[0], red[1]), fmaxf(red[2], red[3]));
  // exp + block sum
  float ls = 0.f;
  for (int s = tid; s < T; s += 256){
    float e = (s <= t) ? __expf(scL[s] - mx) : 0.f;
    wL[s] = e; ls += e;
  }
  #pragma unroll
  for (int o = 32; o > 0; o >>= 1) ls += __shfl_xor(ls, o);
  if ((tid & 63) == 0) red2[tid >> 6] = ls;
  __syncthreads();
  float inv = 1.f / (red2[0] + red2[1] + red2[2] + red2[3]);
  for (int s = tid; s < T; s += 256){
    float wv = wL[s] * inv;
    wL[s] = wv;
    wout[(size_t)bt * T + s] = wv;
  }
  __syncthreads();
  // context: thread per h
  if (tid < H){
    const float* rb = rnn + (size_t)b * T * H + tid;
    float c0 = 0.f, c1 = 0.f, c2 = 0.f, c3 = 0.f;
    int s = 0;
    for (; s + 3 <= t; s += 4){
      c0 += wL[s]     * rb[(size_t)s * H];
      c1 += wL[s + 1] * rb[(size_t)(s + 1) * H];
      c2 += wL[s + 2] * rb[(size_t)(s + 2) * H];
      c3 += wL[s + 3] * rb[(size_t)(s + 3) * H];
    }
    for (; s <= t; ++s) c0 += wL[s] * rb[(size_t)s * H];
    ctxL[tid] = (c0 + c1) + (c2 + c3);
  }
  __syncthreads();
  // out = relu([rnn_row, ctx] @ Wp.T + bp), store bf16
  if (tid < H){
    const float* wp = Wp + (size_t)tid * (2 * H);
    float a0 = 0.f, a1 = 0.f, a2 = 0.f, a3 = 0.f;
    #pragma unroll 8
    for (int k = 0; k < H; k += 4){
      float4 w4 = *(const float4*)(wp + k);
      float4 r4 = *(const float4*)(rrL + k);
      a0 += w4.x * r4.x; a1 += w4.y * r4.y; a2 += w4.z * r4.z; a3 += w4.w * r4.w;
    }
    #pragma unroll 8
    for (int k = 0; k < H; k += 4){
      float4 w4 = *(const float4*)(wp + H + k);
      float4 c4 = *(const float4*)(ctxL + k);
      a0 += w4.x * c4.x; a1 += w4.y * c4.y; a2 += w4.z * c4.z; a3 += w4.w * c4.w;
    }
    float o = bp[tid] + (a0 + a1) + (a2 + a3);
    o = fmaxf(o, 0.f);
    outb[(size_t)bt * H + tid] = f2bf(o);
  }
}

// ---------------- Kernel 5: logits = out @ Wfc.T + bfc  (bf16 MFMA) ----------------
// Grid: 250 blocks, one per 128-col strip of Wfc. B-fragments (128x128 tile) are
// loaded ONCE into registers (32 frags x 4 VGPR = 128 VGPRs); loop over all 16
// 64-row M-tiles reading A straight from global (L2-resident). No LDS, no barriers.
// Write-bound: 131 MB logits store ~21 us floor.
__global__ __launch_bounds__(256, 1) void gemm_kernel(const unsigned short* __restrict__ Ab,
    const unsigned short* __restrict__ Bb, const float* __restrict__ bfc,
    float* __restrict__ Cout){
  int tid = threadIdx.x;
  int l = tid & 63, wv = tid >> 6;
  int lm = l & 15, lq = l >> 4;
  int nBase = blockIdx.x * 128;
  bf16x8 bw[32];
  const unsigned short* bp = Bb + (size_t)(nBase + lm) * H + lq * 8;
  #pragma unroll
  for (int sub = 0; sub < 8; ++sub)
    #pragma unroll
    for (int kk = 0; kk < 4; ++kk)
      bw[sub * 4 + kk] = *(const bf16x8*)(bp + (size_t)sub * 16 * H + kk * 32);
  float bias[8];
  #pragma unroll
  for (int sub = 0; sub < 8; ++sub) bias[sub] = bfc[nBase + lm + sub * 16];
  #pragma unroll 1
  for (int mb = 0; mb < 16; ++mb){
    int rowA = mb * 64 + wv * 16 + lm;
    const unsigned short* ap = Ab + (size_t)rowA * H + lq * 8;
    bf16x8 af[4];
    #pragma unroll
    for (int kk = 0; kk < 4; ++kk) af[kk] = *(const bf16x8*)(ap + kk * 32);
    f32x4 acc[8];
    #pragma unroll
    for (int s = 0; s < 8; ++s) acc[s] = (f32x4){0.f, 0.f, 0.f, 0.f};
    #pragma unroll
    for (int kk = 0; kk < 4; ++kk)
      #pragma unroll
      for (int sub = 0; sub < 8; ++sub)
        acc[sub] = __builtin_amdgcn_mfma_f32_16x16x32_bf16(af[kk], bw[sub * 4 + kk], acc[sub], 0, 0, 0);
    int row0 = mb * 64 + wv * 16 + lq * 4;
    #pragma unroll
    for (int sub = 0; sub < 8; ++sub){
      int c = nBase + lm + sub * 16;
      #pragma unroll
      for (int r = 0; r < 4; ++r)
        Cout[(size_t)(row0 + r) * V + c] = acc[sub][r] + bias[sub];
    }
  }
}

extern "C" void kernel_launch(void* const* d_in, const int* in_sizes, int n_in,
                              void* d_out, int out_size, void* d_ws, size_t ws_size,
                              hipStream_t stream){
  const int*   x      = (const int*)d_in[0];
  const float* hidden = (const float*)d_in[1];
  const float* table  = (const float*)d_in[2];
  const float* W_ih   = (const float*)d_in[3];
  const float* W_hh   = (const float*)d_in[4];
  const float* b_ih   = (const float*)d_in[5];
  const float* b_hh   = (const float*)d_in[6];
  const float* W1     = (const float*)d_in[7];
  const float* W2     = (const float*)d_in[8];
  const float* v      = (const float*)d_in[9];
  const float* Wp     = (const float*)d_in[10];
  const float* bp     = (const float*)d_in[11];
  const float* Wfc    = (const float*)d_in[12];
  const float* bfc    = (const float*)d_in[13];

  float* out     = (float*)d_out;
  float* logits  = out;                              // (B,T,V)
  float* hid_out = out + (size_t)B * T * V;          // (1,B,H)
  float* w_out   = hid_out + (size_t)B * H;          // (B,T,T)

  float* xp  = (float*)d_ws;
  float* rnn = xp  + (size_t)B * T * H;
  float* q   = rnn + (size_t)B * T * H;
  float* ky  = q   + (size_t)B * T * H;
  unsigned short* outb = (unsigned short*)(ky + (size_t)B * T * H);
  unsigned short* wfcb = outb + (size_t)B * T * H;

  prep_kernel<<<B * T + (V * H) / 1024, 128, 0, stream>>>(x, table, W_ih, b_ih, b_hh, Wfc, xp, wfcb);
  rnn_kernel<<<B, 256, 0, stream>>>(xp, hidden, W_hh, rnn, hid_out);
  qk_kernel<<<B * T, 256, 0, stream>>>(rnn, W1, W2, q, ky);
  attn_kernel<<<B * T, 256, 0, stream>>>(rnn, q, ky, v, Wp, bp, w_out, outb);
  gemm_kernel<<<V / 128, 256, 0, stream>>>(outb, wfcb, bfc, logits);
}

// Round 3
// 494.260 us; speedup vs baseline: 1.0385x; 1.0004x over previous
//
#include <hip/hip_runtime.h>
#include <hip/hip_bf16.h>

#define T 512
#define H 128
#define V 32000
#define B 2

typedef __attribute__((ext_vector_type(8))) short bf16x8;
typedef __attribute__((ext_vector_type(4))) float f32x4;

__device__ __forceinline__ unsigned short f2bf(float f){
  unsigned int u = __float_as_uint(f);
  u = (u + 0x7FFFu + ((u >> 16) & 1u)) >> 16;
  return (unsigned short)u;
}

__device__ __forceinline__ float fast_tanh(float x){
  x = fminf(8.f, fmaxf(-8.f, x));
  float e = __expf(2.f * x);
  return (e - 1.f) / (e + 1.f);
}

// ---------------- Kernel 1: prep = embedding/input-projection + Wfc->bf16 ----------------
__global__ __launch_bounds__(128) void prep_kernel(const int* __restrict__ x,
    const float* __restrict__ table, const float* __restrict__ W_ih,
    const float* __restrict__ b_ih, const float* __restrict__ b_hh,
    const float* __restrict__ Wfc,
    float* __restrict__ xp, unsigned short* __restrict__ wfcb){
  int blk = blockIdx.x;
  int tid = threadIdx.x;
  __shared__ __align__(16) float e[32];
  if (blk < B * T){
    if (tid < 32) e[tid] = table[(size_t)x[blk] * 32 + tid];
    __syncthreads();
    const float* wr = W_ih + tid * 32;
    float a0 = 0.f, a1 = 0.f, a2 = 0.f, a3 = 0.f;
    #pragma unroll
    for (int k = 0; k < 32; k += 4){
      float4 w4 = *(const float4*)(wr + k);
      float4 e4 = *(const float4*)(e + k);
      a0 += w4.x * e4.x; a1 += w4.y * e4.y; a2 += w4.z * e4.z; a3 += w4.w * e4.w;
    }
    xp[(size_t)blk * H + tid] = (a0 + a1) + (a2 + a3) + b_ih[tid] + b_hh[tid];
  } else {
    size_t base = (size_t)(blk - B * T) * 1024 + (size_t)tid * 8;
    float4 f0 = *(const float4*)(Wfc + base);
    float4 f1 = *(const float4*)(Wfc + base + 4);
    ushort4 o0, o1;
    o0.x = f2bf(f0.x); o0.y = f2bf(f0.y); o0.z = f2bf(f0.z); o0.w = f2bf(f0.w);
    o1.x = f2bf(f1.x); o1.y = f2bf(f1.y); o1.z = f2bf(f1.z); o1.w = f2bf(f1.w);
    *(ushort4*)(wfcb + base) = o0;
    *(ushort4*)(wfcb + base + 4) = o1;
  }
}

// ---------------- Kernel 2: serial RNN scan, one block per batch chain ----------------
// 256 threads: thread t -> output i = t>>1, k-half = t&1. W_hh held in 16 NAMED
// float4 registers (an indexed array gets SROA'd to scratch -> round 1/2's 48-VGPR
// spill and 247us). h double-buffered in LDS, xp prefetched one step ahead.
__global__ __launch_bounds__(256, 1) void rnn_kernel(const float* __restrict__ xp,
    const float* __restrict__ hidden, const float* __restrict__ W_hh,
    float* __restrict__ rnn, float* __restrict__ hid_out){
  int b = blockIdx.x;
  int tid = threadIdx.x;
  int i = tid >> 1, half = tid & 1;
  const float* wrow = W_hh + (size_t)i * H + half * 64;
#define WLOAD(n) float4 W##n = *(const float4*)(wrow + 4 * n);
  WLOAD(0) WLOAD(1) WLOAD(2) WLOAD(3) WLOAD(4) WLOAD(5) WLOAD(6) WLOAD(7)
  WLOAD(8) WLOAD(9) WLOAD(10) WLOAD(11) WLOAD(12) WLOAD(13) WLOAD(14) WLOAD(15)
#undef WLOAD
  __shared__ __align__(16) float hb[2][H];
  if (half == 0) hb[0][i] = hidden[b * H + i];
  __syncthreads();
  const float* xpp = xp + (size_t)b * T * H + i;
  float xv = xpp[0];
  float hn = 0.f;
  int cur = 0;
  for (int step = 0; step < T; ++step){
    float xn = (step < T - 1) ? xpp[(size_t)(step + 1) * H] : 0.f;
    const float* hs = hb[cur] + half * 64;
    float a0 = 0.f, a1 = 0.f, a2 = 0.f, a3 = 0.f;
#define FMA4(n) { float4 hv = *(const float4*)(hs + 4 * n); \
    a0 = fmaf(hv.x, W##n.x, a0); a1 = fmaf(hv.y, W##n.y, a1); \
    a2 = fmaf(hv.z, W##n.z, a2); a3 = fmaf(hv.w, W##n.w, a3); }
    FMA4(0) FMA4(1) FMA4(2) FMA4(3) FMA4(4) FMA4(5) FMA4(6) FMA4(7)
    FMA4(8) FMA4(9) FMA4(10) FMA4(11) FMA4(12) FMA4(13) FMA4(14) FMA4(15)
#undef FMA4
    float sum = (a0 + a1) + (a2 + a3);
    sum += __shfl_xor(sum, 1);
    hn = fast_tanh(xv + sum);
    if (half == 0){
      hb[cur ^ 1][i] = hn;
      rnn[(size_t)b * T * H + (size_t)step * H + i] = hn;
    }
    __syncthreads();
    xv = xn;
    cur ^= 1;
  }
  if (half == 0) hid_out[b * H + i] = hn;
}

// ---------------- Kernel 3: query/key projections ----------------
__global__ __launch_bounds__(256) void qk_kernel(const float* __restrict__ rnn,
    const float* __restrict__ W1, const float* __restrict__ W2,
    float* __restrict__ q, float* __restrict__ ky){
  int bt = blockIdx.x;
  int tid = threadIdx.x;
  __shared__ __align__(16) float r[H];
  if (tid < H) r[tid] = rnn[(size_t)bt * H + tid];
  __syncthreads();
  int i = tid & (H - 1);
  const float* wrow = ((tid < H) ? W1 : W2) + (size_t)i * H;
  float a0 = 0.f, a1 = 0.f, a2 = 0.f, a3 = 0.f;
  #pragma unroll 8
  for (int k = 0; k < H; k += 4){
    float4 w4 = *(const float4*)(wrow + k);
    float4 r4 = *(const float4*)(r + k);
    a0 += w4.x * r4.x; a1 += w4.y * r4.y; a2 += w4.z * r4.z; a3 += w4.w * r4.w;
  }
  float res = (a0 + a1) + (a2 + a3);
  if (tid < H) q[(size_t)bt * H + i] = res;
  else         ky[(size_t)bt * H + i] = res;
}

// ---------------- Kernel 4: attention scores + softmax + context + Wp/relu ----------------
__global__ __launch_bounds__(256) void attn_kernel(const float* __restrict__ rnn,
    const float* __restrict__ q, const float* __restrict__ ky,
    const float* __restrict__ v, const float* __restrict__ Wp,
    const float* __restrict__ bp, float* __restrict__ wout,
    unsigned short* __restrict__ outb){
  int bt = blockIdx.x;
  int b = bt >> 9, t = bt & (T - 1);
  int tid = threadIdx.x;
  __shared__ __align__(16) float qL[H], vL[H], rrL[H], ctxL[H];
  __shared__ __align__(16) float scL[T], wL[T];
  __shared__ float red[4], red2[4];
  if (tid < H){
    qL[tid]  = q[(size_t)bt * H + tid];
    vL[tid]  = v[tid];
    rrL[tid] = rnn[(size_t)bt * H + tid];
  }
  __syncthreads();
  // scores: thread per s
  for (int s = tid; s < T; s += 256){
    float sc = -1e30f;
    if (s <= t){
      const float* kr = ky + (size_t)(b * T + s) * H;
      float a0 = 0.f, a1 = 0.f, a2 = 0.f, a3 = 0.f;
      #pragma unroll 4
      for (int h = 0; h < H; h += 4){
        float4 kv = *(const float4*)(kr + h);
        float4 qv = *(const float4*)(qL + h);
        float4 vv = *(const float4*)(vL + h);
        a0 += fast_tanh(qv.x + kv.x) * vv.x;
        a1 += fast_tanh(qv.y + kv.y) * vv.y;
        a2 += fast_tanh(qv.z + kv.z) * vv.z;
        a3 += fast_tanh(qv.w + kv.w) * vv.w;
      }
      sc = (a0 + a1) + (a2 + a3);
    }
    scL[s] = sc;
  }
  __syncthreads();
  // block max
  float m = -1e30f;
  for (int s = tid; s < T; s += 256) m = fmaxf(m, scL[s]);
  #pragma unroll
  for (int o = 32; o > 0; o >>= 1) m = fmaxf(m, __shfl_xor(m, o));
  if ((tid & 63) == 0) red[tid >> 6] = m;
  __syncthreads();
  float mx = fmaxf(fmaxf(red[0], red[1]), fmaxf(red[2], red[3]));
  // exp + block sum
  float ls = 0.f;
  for (int s = tid; s < T; s += 256){
    float e = (s <= t) ? __expf(scL[s] - mx) : 0.f;
    wL[s] = e; ls += e;
  }
  #pragma unroll
  for (int o = 32; o > 0; o >>= 1) ls += __shfl_xor(ls, o);
  if ((tid & 63) == 0) red2[tid >> 6] = ls;
  __syncthreads();
  float inv = 1.f / (red2[0] + red2[1] + red2[2] + red2[3]);
  for (int s = tid; s < T; s += 256){
    float wv = wL[s] * inv;
    wL[s] = wv;
    wout[(size_t)bt * T + s] = wv;
  }
  __syncthreads();
  // context: thread per h
  if (tid < H){
    const float* rb = rnn + (size_t)b * T * H + tid;
    float c0 = 0.f, c1 = 0.f, c2 = 0.f, c3 = 0.f;
    int s = 0;
    for (; s + 3 <= t; s += 4){
      c0 += wL[s]     * rb[(size_t)s * H];
      c1 += wL[s + 1] * rb[(size_t)(s + 1) * H];
      c2 += wL[s + 2] * rb[(size_t)(s + 2) * H];
      c3 += wL[s + 3] * rb[(size_t)(s + 3) * H];
    }
    for (; s <= t; ++s) c0 += wL[s] * rb[(size_t)s * H];
    ctxL[tid] = (c0 + c1) + (c2 + c3);
  }
  __syncthreads();
  // out = relu([rnn_row, ctx] @ Wp.T + bp), store bf16
  if (tid < H){
    const float* wp = Wp + (size_t)tid * (2 * H);
    float a0 = 0.f, a1 = 0.f, a2 = 0.f, a3 = 0.f;
    #pragma unroll 8
    for (int k = 0; k < H; k += 4){
      float4 w4 = *(const float4*)(wp + k);
      float4 r4 = *(const float4*)(rrL + k);
      a0 += w4.x * r4.x; a1 += w4.y * r4.y; a2 += w4.z * r4.z; a3 += w4.w * r4.w;
    }
    #pragma unroll 8
    for (int k = 0; k < H; k += 4){
      float4 w4 = *(const float4*)(wp + H + k);
      float4 c4 = *(const float4*)(ctxL + k);
      a0 += w4.x * c4.x; a1 += w4.y * c4.y; a2 += w4.z * c4.z; a3 += w4.w * c4.w;
    }
    float o = bp[tid] + (a0 + a1) + (a2 + a3);
    o = fmaxf(o, 0.f);
    outb[(size_t)bt * H + tid] = f2bf(o);
  }
}

// ---------------- Kernel 5: logits = out @ Wfc.T + bfc  (bf16 MFMA) ----------------
__global__ __launch_bounds__(256, 1) void gemm_kernel(const unsigned short* __restrict__ Ab,
    const unsigned short* __restrict__ Bb, const float* __restrict__ bfc,
    float* __restrict__ Cout){
  int tid = threadIdx.x;
  int l = tid & 63, wv = tid >> 6;
  int lm = l & 15, lq = l >> 4;
  int nBase = blockIdx.x * 128;
  bf16x8 bw[32];
  const unsigned short* bp = Bb + (size_t)(nBase + lm) * H + lq * 8;
  #pragma unroll
  for (int sub = 0; sub < 8; ++sub)
    #pragma unroll
    for (int kk = 0; kk < 4; ++kk)
      bw[sub * 4 + kk] = *(const bf16x8*)(bp + (size_t)sub * 16 * H + kk * 32);
  float bias[8];
  #pragma unroll
  for (int sub = 0; sub < 8; ++sub) bias[sub] = bfc[nBase + lm + sub * 16];
  #pragma unroll 1
  for (int mb = 0; mb < 16; ++mb){
    int rowA = mb * 64 + wv * 16 + lm;
    const unsigned short* ap = Ab + (size_t)rowA * H + lq * 8;
    bf16x8 af[4];
    #pragma unroll
    for (int kk = 0; kk < 4; ++kk) af[kk] = *(const bf16x8*)(ap + kk * 32);
    f32x4 acc[8];
    #pragma unroll
    for (int s = 0; s < 8; ++s) acc[s] = (f32x4){0.f, 0.f, 0.f, 0.f};
    #pragma unroll
    for (int kk = 0; kk < 4; ++kk)
      #pragma unroll
      for (int sub = 0; sub < 8; ++sub)
        acc[sub] = __builtin_amdgcn_mfma_f32_16x16x32_bf16(af[kk], bw[sub * 4 + kk], acc[sub], 0, 0, 0);
    int row0 = mb * 64 + wv * 16 + lq * 4;
    #pragma unroll
    for (int sub = 0; sub < 8; ++sub){
      int c = nBase + lm + sub * 16;
      #pragma unroll
      for (int r = 0; r < 4; ++r)
        Cout[(size_t)(row0 + r) * V + c] = acc[sub][r] + bias[sub];
    }
  }
}

extern "C" void kernel_launch(void* const* d_in, const int* in_sizes, int n_in,
                              void* d_out, int out_size, void* d_ws, size_t ws_size,
                              hipStream_t stream){
  const int*   x      = (const int*)d_in[0];
  const float* hidden = (const float*)d_in[1];
  const float* table  = (const float*)d_in[2];
  const float* W_ih   = (const float*)d_in[3];
  const float* W_hh   = (const float*)d_in[4];
  const float* b_ih   = (const float*)d_in[5];
  const float* b_hh   = (const float*)d_in[6];
  const float* W1     = (const float*)d_in[7];
  const float* W2     = (const float*)d_in[8];
  const float* v      = (const float*)d_in[9];
  const float* Wp     = (const float*)d_in[10];
  const float* bp     = (const float*)d_in[11];
  const float* Wfc    = (const float*)d_in[12];
  const float* bfc    = (const float*)d_in[13];

  float* out     = (float*)d_out;
  float* logits  = out;                              // (B,T,V)
  float* hid_out = out + (size_t)B * T * V;          // (1,B,H)
  float* w_out   = hid_out + (size_t)B * H;          // (B,T,T)

  float* xp  = (float*)d_ws;
  float* rnn = xp  + (size_t)B * T * H;
  float* q   = rnn + (size_t)B * T * H;
  float* ky  = q   + (size_t)B * T * H;
  unsigned short* outb = (unsigned short*)(ky + (size_t)B * T * H);
  unsigned short* wfcb = outb + (size_t)B * T * H;

  prep_kernel<<<B * T + (V * H) / 1024, 128, 0, stream>>>(x, table, W_ih, b_ih, b_hh, Wfc, xp, wfcb);
  rnn_kernel<<<B, 256, 0, stream>>>(xp, hidden, W_hh, rnn, hid_out);
  qk_kernel<<<B * T, 256, 0, stream>>>(rnn, W1, W2, q, ky);
  attn_kernel<<<B * T, 256, 0, stream>>>(rnn, q, ky, v, Wp, bp, w_out, outb);
  gemm_kernel<<<V / 128, 256, 0, stream>>>(outb, wfcb, bfc, logits);
}

// Round 4
// 473.644 us; speedup vs baseline: 1.0837x; 1.0435x over previous
//
#include <hip/hip_runtime.h>
#include <hip/hip_bf16.h>

#define T 512
#define H 128
#define V 32000
#define B 2

typedef __attribute__((ext_vector_type(8))) short bf16x8;
typedef __attribute__((ext_vector_type(4))) float f32x4;

__device__ __forceinline__ unsigned short f2bf(float f){
  unsigned int u = __float_as_uint(f);
  u = (u + 0x7FFFu + ((u >> 16) & 1u)) >> 16;
  return (unsigned short)u;
}

__device__ __forceinline__ float fast_tanh(float x){
  x = fminf(8.f, fmaxf(-8.f, x));
  float e = __expf(2.f * x);
  return (e - 1.f) / (e + 1.f);
}

// ---------------- Kernel 1: prep = embedding/input-projection + Wfc->bf16 ----------------
__global__ __launch_bounds__(128) void prep_kernel(const int* __restrict__ x,
    const float* __restrict__ table, const float* __restrict__ W_ih,
    const float* __restrict__ b_ih, const float* __restrict__ b_hh,
    const float* __restrict__ Wfc,
    float* __restrict__ xp, unsigned short* __restrict__ wfcb){
  int blk = blockIdx.x;
  int tid = threadIdx.x;
  __shared__ __align__(16) float e[32];
  if (blk < B * T){
    if (tid < 32) e[tid] = table[(size_t)x[blk] * 32 + tid];
    __syncthreads();
    const float* wr = W_ih + tid * 32;
    float a0 = 0.f, a1 = 0.f, a2 = 0.f, a3 = 0.f;
    #pragma unroll
    for (int k = 0; k < 32; k += 4){
      float4 w4 = *(const float4*)(wr + k);
      float4 e4 = *(const float4*)(e + k);
      a0 += w4.x * e4.x; a1 += w4.y * e4.y; a2 += w4.z * e4.z; a3 += w4.w * e4.w;
    }
    xp[(size_t)blk * H + tid] = (a0 + a1) + (a2 + a3) + b_ih[tid] + b_hh[tid];
  } else {
    size_t base = (size_t)(blk - B * T) * 1024 + (size_t)tid * 8;
    float4 f0 = *(const float4*)(Wfc + base);
    float4 f1 = *(const float4*)(Wfc + base + 4);
    ushort4 o0, o1;
    o0.x = f2bf(f0.x); o0.y = f2bf(f0.y); o0.z = f2bf(f0.z); o0.w = f2bf(f0.w);
    o1.x = f2bf(f1.x); o1.y = f2bf(f1.y); o1.z = f2bf(f1.z); o1.w = f2bf(f1.w);
    *(ushort4*)(wfcb + base) = o0;
    *(ushort4*)(wfcb + base + 4) = o1;
  }
}

// ---------------- Kernel 2: serial RNN scan, one block per batch chain ----------------
// 512 threads: thread -> output i = tid>>2, k-quarter q = tid&3 (32 weights each).
// Weights pinned in registers via empty inline asm: RA cannot rematerialize an asm
// result, so they stay resident (rounds 1-3: compiler rematerialized the invariant
// weight loads inside the loop -> L1 reload latency every step, 247us @ 48 VGPRs).
__global__ __launch_bounds__(512, 1) void rnn_kernel(const float* __restrict__ xp,
    const float* __restrict__ hidden, const float* __restrict__ W_hh,
    float* __restrict__ rnn, float* __restrict__ hid_out){
  int b = blockIdx.x;
  int tid = threadIdx.x;
  int i = tid >> 2, q = tid & 3;
  const float* wrow = W_hh + (size_t)i * H + q * 32;
  f32x4 W0 = *(const f32x4*)(wrow);
  f32x4 W1 = *(const f32x4*)(wrow + 4);
  f32x4 W2 = *(const f32x4*)(wrow + 8);
  f32x4 W3 = *(const f32x4*)(wrow + 12);
  f32x4 W4 = *(const f32x4*)(wrow + 16);
  f32x4 W5 = *(const f32x4*)(wrow + 20);
  f32x4 W6 = *(const f32x4*)(wrow + 24);
  f32x4 W7 = *(const f32x4*)(wrow + 28);
  asm volatile("" : "+v"(W0), "+v"(W1), "+v"(W2), "+v"(W3),
                    "+v"(W4), "+v"(W5), "+v"(W6), "+v"(W7));
  __shared__ __align__(16) float hb[2][H];
  if (q == 0) hb[0][i] = hidden[b * H + i];
  __syncthreads();
  const float* xpp = xp + (size_t)b * T * H + i;
  float xv = xpp[0];
  float hn = 0.f;
  int cur = 0;
  for (int step = 0; step < T; ++step){
    float xn = (step < T - 1) ? xpp[(size_t)(step + 1) * H] : 0.f;
    const float* hs = hb[cur] + q * 32;
    float a0 = 0.f, a1 = 0.f, a2 = 0.f, a3 = 0.f;
#define FMA4(n) { f32x4 hv = *(const f32x4*)(hs + 4 * n); \
    a0 = fmaf(hv.x, W##n.x, a0); a1 = fmaf(hv.y, W##n.y, a1); \
    a2 = fmaf(hv.z, W##n.z, a2); a3 = fmaf(hv.w, W##n.w, a3); }
    FMA4(0) FMA4(1) FMA4(2) FMA4(3) FMA4(4) FMA4(5) FMA4(6) FMA4(7)
#undef FMA4
    float sum = (a0 + a1) + (a2 + a3);
    sum += __shfl_xor(sum, 1);
    sum += __shfl_xor(sum, 2);
    hn = fast_tanh(xv + sum);
    if (q == 0){
      hb[cur ^ 1][i] = hn;
      rnn[(size_t)b * T * H + (size_t)step * H + i] = hn;
    }
    __syncthreads();
    xv = xn;
    cur ^= 1;
  }
  if (q == 0) hid_out[b * H + i] = hn;
}

// ---------------- Kernel 3: query/key projections ----------------
__global__ __launch_bounds__(256) void qk_kernel(const float* __restrict__ rnn,
    const float* __restrict__ W1, const float* __restrict__ W2,
    float* __restrict__ q, float* __restrict__ ky){
  int bt = blockIdx.x;
  int tid = threadIdx.x;
  __shared__ __align__(16) float r[H];
  if (tid < H) r[tid] = rnn[(size_t)bt * H + tid];
  __syncthreads();
  int i = tid & (H - 1);
  const float* wrow = ((tid < H) ? W1 : W2) + (size_t)i * H;
  float a0 = 0.f, a1 = 0.f, a2 = 0.f, a3 = 0.f;
  #pragma unroll 8
  for (int k = 0; k < H; k += 4){
    float4 w4 = *(const float4*)(wrow + k);
    float4 r4 = *(const float4*)(r + k);
    a0 += w4.x * r4.x; a1 += w4.y * r4.y; a2 += w4.z * r4.z; a3 += w4.w * r4.w;
  }
  float res = (a0 + a1) + (a2 + a3);
  if (tid < H) q[(size_t)bt * H + i] = res;
  else         ky[(size_t)bt * H + i] = res;
}

// ---------------- Kernel 4: attention scores + softmax + context + Wp/relu ----------------
__global__ __launch_bounds__(256) void attn_kernel(const float* __restrict__ rnn,
    const float* __restrict__ q, const float* __restrict__ ky,
    const float* __restrict__ v, const float* __restrict__ Wp,
    const float* __restrict__ bp, float* __restrict__ wout,
    unsigned short* __restrict__ outb){
  int bt = blockIdx.x;
  int b = bt >> 9, t = bt & (T - 1);
  int tid = threadIdx.x;
  __shared__ __align__(16) float qL[H], vL[H], rrL[H], ctxL[H];
  __shared__ __align__(16) float scL[T], wL[T];
  __shared__ float red[4], red2[4];
  if (tid < H){
    qL[tid]  = q[(size_t)bt * H + tid];
    vL[tid]  = v[tid];
    rrL[tid] = rnn[(size_t)bt * H + tid];
  }
  __syncthreads();
  for (int s = tid; s < T; s += 256){
    float sc = -1e30f;
    if (s <= t){
      const float* kr = ky + (size_t)(b * T + s) * H;
      float a0 = 0.f, a1 = 0.f, a2 = 0.f, a3 = 0.f;
      #pragma unroll 4
      for (int h = 0; h < H; h += 4){
        float4 kv = *(const float4*)(kr + h);
        float4 qv = *(const float4*)(qL + h);
        float4 vv = *(const float4*)(vL + h);
        a0 += fast_tanh(qv.x + kv.x) * vv.x;
        a1 += fast_tanh(qv.y + kv.y) * vv.y;
        a2 += fast_tanh(qv.z + kv.z) * vv.z;
        a3 += fast_tanh(qv.w + kv.w) * vv.w;
      }
      sc = (a0 + a1) + (a2 + a3);
    }
    scL[s] = sc;
  }
  __syncthreads();
  float m = -1e30f;
  for (int s = tid; s < T; s += 256) m = fmaxf(m, scL[s]);
  #pragma unroll
  for (int o = 32; o > 0; o >>= 1) m = fmaxf(m, __shfl_xor(m, o));
  if ((tid & 63) == 0) red[tid >> 6] = m;
  __syncthreads();
  float mx = fmaxf(fmaxf(red[0], red[1]), fmaxf(red[2], red[3]));
  float ls = 0.f;
  for (int s = tid; s < T; s += 256){
    float e = (s <= t) ? __expf(scL[s] - mx) : 0.f;
    wL[s] = e; ls += e;
  }
  #pragma unroll
  for (int o = 32; o > 0; o >>= 1) ls += __shfl_xor(ls, o);
  if ((tid & 63) == 0) red2[tid >> 6] = ls;
  __syncthreads();
  float inv = 1.f / (red2[0] + red2[1] + red2[2] + red2[3]);
  for (int s = tid; s < T; s += 256){
    float wv = wL[s] * inv;
    wL[s] = wv;
    wout[(size_t)bt * T + s] = wv;
  }
  __syncthreads();
  if (tid < H){
    const float* rb = rnn + (size_t)b * T * H + tid;
    float c0 = 0.f, c1 = 0.f, c2 = 0.f, c3 = 0.f;
    int s = 0;
    for (; s + 3 <= t; s += 4){
      c0 += wL[s]     * rb[(size_t)s * H];
      c1 += wL[s + 1] * rb[(size_t)(s + 1) * H];
      c2 += wL[s + 2] * rb[(size_t)(s + 2) * H];
      c3 += wL[s + 3] * rb[(size_t)(s + 3) * H];
    }
    for (; s <= t; ++s) c0 += wL[s] * rb[(size_t)s * H];
    ctxL[tid] = (c0 + c1) + (c2 + c3);
  }
  __syncthreads();
  if (tid < H){
    const float* wp = Wp + (size_t)tid * (2 * H);
    float a0 = 0.f, a1 = 0.f, a2 = 0.f, a3 = 0.f;
    #pragma unroll 8
    for (int k = 0; k < H; k += 4){
      float4 w4 = *(const float4*)(wp + k);
      float4 r4 = *(const float4*)(rrL + k);
      a0 += w4.x * r4.x; a1 += w4.y * r4.y; a2 += w4.z * r4.z; a3 += w4.w * r4.w;
    }
    #pragma unroll 8
    for (int k = 0; k < H; k += 4){
      float4 w4 = *(const float4*)(wp + H + k);
      float4 c4 = *(const float4*)(ctxL + k);
      a0 += w4.x * c4.x; a1 += w4.y * c4.y; a2 += w4.z * c4.z; a3 += w4.w * c4.w;
    }
    float o = bp[tid] + (a0 + a1) + (a2 + a3);
    o = fmaxf(o, 0.f);
    outb[(size_t)bt * H + tid] = f2bf(o);
  }
}

// ---------------- Kernel 5: logits = out @ Wfc.T + bfc  (bf16 MFMA) ----------------
__global__ __launch_bounds__(256, 1) void gemm_kernel(const unsigned short* __restrict__ Ab,
    const unsigned short* __restrict__ Bb, const float* __restrict__ bfc,
    float* __restrict__ Cout){
  int tid = threadIdx.x;
  int l = tid & 63, wv = tid >> 6;
  int lm = l & 15, lq = l >> 4;
  int nBase = blockIdx.x * 128;
  bf16x8 bw[32];
  const unsigned short* bp = Bb + (size_t)(nBase + lm) * H + lq * 8;
  #pragma unroll
  for (int sub = 0; sub < 8; ++sub)
    #pragma unroll
    for (int kk = 0; kk < 4; ++kk)
      bw[sub * 4 + kk] = *(const bf16x8*)(bp + (size_t)sub * 16 * H + kk * 32);
  float bias[8];
  #pragma unroll
  for (int sub = 0; sub < 8; ++sub) bias[sub] = bfc[nBase + lm + sub * 16];
  #pragma unroll 1
  for (int mb = 0; mb < 16; ++mb){
    int rowA = mb * 64 + wv * 16 + lm;
    const unsigned short* ap = Ab + (size_t)rowA * H + lq * 8;
    bf16x8 af[4];
    #pragma unroll
    for (int kk = 0; kk < 4; ++kk) af[kk] = *(const bf16x8*)(ap + kk * 32);
    f32x4 acc[8];
    #pragma unroll
    for (int s = 0; s < 8; ++s) acc[s] = (f32x4){0.f, 0.f, 0.f, 0.f};
    #pragma unroll
    for (int kk = 0; kk < 4; ++kk)
      #pragma unroll
      for (int sub = 0; sub < 8; ++sub)
        acc[sub] = __builtin_amdgcn_mfma_f32_16x16x32_bf16(af[kk], bw[sub * 4 + kk], acc[sub], 0, 0, 0);
    int row0 = mb * 64 + wv * 16 + lq * 4;
    #pragma unroll
    for (int sub = 0; sub < 8; ++sub){
      int c = nBase + lm + sub * 16;
      #pragma unroll
      for (int r = 0; r < 4; ++r)
        Cout[(size_t)(row0 + r) * V + c] = acc[sub][r] + bias[sub];
    }
  }
}

extern "C" void kernel_launch(void* const* d_in, const int* in_sizes, int n_in,
                              void* d_out, int out_size, void* d_ws, size_t ws_size,
                              hipStream_t stream){
  const int*   x      = (const int*)d_in[0];
  const float* hidden = (const float*)d_in[1];
  const float* table  = (const float*)d_in[2];
  const float* W_ih   = (const float*)d_in[3];
  const float* W_hh   = (const float*)d_in[4];
  const float* b_ih   = (const float*)d_in[5];
  const float* b_hh   = (const float*)d_in[6];
  const float* W1     = (const float*)d_in[7];
  const float* W2     = (const float*)d_in[8];
  const float* v      = (const float*)d_in[9];
  const float* Wp     = (const float*)d_in[10];
  const float* bp     = (const float*)d_in[11];
  const float* Wfc    = (const float*)d_in[12];
  const float* bfc    = (const float*)d_in[13];

  float* out     = (float*)d_out;
  float* logits  = out;                              // (B,T,V)
  float* hid_out = out + (size_t)B * T * V;          // (1,B,H)
  float* w_out   = hid_out + (size_t)B * H;          // (B,T,T)

  float* xp  = (float*)d_ws;
  float* rnn = xp  + (size_t)B * T * H;
  float* q   = rnn + (size_t)B * T * H;
  float* ky  = q   + (size_t)B * T * H;
  unsigned short* outb = (unsigned short*)(ky + (size_t)B * T * H);
  unsigned short* wfcb = outb + (size_t)B * T * H;

  prep_kernel<<<B * T + (V * H) / 1024, 128, 0, stream>>>(x, table, W_ih, b_ih, b_hh, Wfc, xp, wfcb);
  rnn_kernel<<<B, 512, 0, stream>>>(xp, hidden, W_hh, rnn, hid_out);
  qk_kernel<<<B * T, 256, 0, stream>>>(rnn, W1, W2, q, ky);
  attn_kernel<<<B * T, 256, 0, stream>>>(rnn, q, ky, v, Wp, bp, w_out, outb);
  gemm_kernel<<<V / 128, 256, 0, stream>>>(outb, wfcb, bfc, logits);
}